// Round 9
// baseline (391.180 us; speedup 1.0000x reference)
//
#include <hip/hip_runtime.h>
#include <hip/hip_fp16.h>

#define NN 50000     // nodes
#define NE 800000    // edges
#define DD 64        // embedding dim
#define GG 64        // graphs
#define VV 30        // node label vocab
#define CAP 48       // bucket capacity per node (in-degree ~ Poisson(16); P(>=48) ~ 1e-9)
#define NB ((NN + 63) / 64)   // 782 bins of 64 nodes
#define BCAP 1280             // per-bin edge capacity: Poisson(1024) mean + 8 sigma

// ---- bf16 helpers (RNE) ----
__device__ inline unsigned short f2bf(float f) {
    unsigned u = __float_as_uint(f);
    return (unsigned short)((u + 0x7FFF + ((u >> 16) & 1)) >> 16);
}
__device__ inline float bf2f(unsigned short s) {
    return __uint_as_float(((unsigned)s) << 16);
}
// ---- packed edge payload: src (lo16) | fp16(ea) (hi16) ----
__device__ inline unsigned pack_edge(int s, float ea) {
    return (unsigned)s | ((unsigned)__half_as_ushort(__float2half_rn(ea)) << 16);
}
__device__ inline int unpack_src(unsigned p) { return (int)(p & 0xFFFFu); }
__device__ inline float unpack_ea(unsigned p) {
    return __half2float(__ushort_as_half((unsigned short)(p >> 16)));
}

// ------- pass A: bin edges by dst>>6; dense cursor-scatter (line-coalescing) -------
__global__ void k_binA(const int* __restrict__ src, const int* __restrict__ dst,
                       const float* __restrict__ ea,
                       int* __restrict__ bincur, uint2* __restrict__ binned) {
    int e = blockIdx.x * blockDim.x + threadIdx.x;
    if (e < NE) {
        int t = dst[e];
        int bin = t >> 6;
        int p = atomicAdd(&bincur[bin], 1);
        if (p < BCAP)
            binned[(size_t)bin * BCAP + p] = make_uint2(pack_edge(src[e], ea[e]),
                                                        (unsigned)(t & 63));
    }
}

// ------- pass B: per-bin LDS-counter bucket fill + degree/dis computation ----------
__global__ __launch_bounds__(256) void k_binB(const int* __restrict__ bincur,
                                              const uint2* __restrict__ binned,
                                              unsigned* __restrict__ ep,
                                              int* __restrict__ cnt,
                                              float* __restrict__ dis) {
    __shared__ int   lcnt[64];
    __shared__ float lsum[64];
    int t = threadIdx.x, bin = blockIdx.x;
    if (t < 64) { lcnt[t] = 0; lsum[t] = 0.f; }
    __syncthreads();
    int n = min(bincur[bin], BCAP);
    const uint2* bp = binned + (size_t)bin * BCAP;
    for (int i = t; i < n; i += 256) {
        uint2 u = bp[i];
        int dl = (int)u.y;
        int p = atomicAdd(&lcnt[dl], 1);
        if (p < CAP) ep[((size_t)(bin * 64 + dl)) * CAP + p] = u.x;
        atomicAdd(&lsum[dl], unpack_ea(u.x));
    }
    __syncthreads();
    if (t < 64) {
        int node = bin * 64 + t;
        if (node < NN) {
            cnt[node] = lcnt[t];
            dis[node] = 1.0f / sqrtf(1.0f + lsum[t]);   // self loop weight 1
        }
    }
}

// ------- tiny dense: E1 = emb @ W1  (30x64 @ 64x64) -------------------------------
__global__ __launch_bounds__(256) void k_emb_mm(const float* __restrict__ emb,
                                                const float* __restrict__ W,
                                                float* __restrict__ E1) {
    int t = threadIdx.x;
    int d = t & 63;
    for (int v = t >> 6; v < VV; v += 4) {
        float acc = 0.f;
        #pragma unroll
        for (int k = 0; k < 64; k++) acc = fmaf(emb[v * 64 + k], W[k * 64 + d], acc);
        E1[v * 64 + d] = acc;
    }
}

// ------- layer 1 fused: h1 = relu( sum_in w*E1[x_s] + dis^2*E1[x_i] + b1 ) --------
__global__ __launch_bounds__(256) void k_layer1(const int* __restrict__ cnt,
                                                const unsigned* __restrict__ ep,
                                                const float* __restrict__ dis,
                                                const int* __restrict__ x,
                                                const float* __restrict__ E1,
                                                const float* __restrict__ bias,
                                                float* __restrict__ A) {
    __shared__ float El[VV * 64];
    int t = threadIdx.x;
    for (int i = t; i < VV * 64; i += 256) El[i] = E1[i];
    __syncthreads();
    int node = blockIdx.x * 4 + (t >> 6);   // 1 wave per node
    int d = t & 63;
    if (node >= NN) return;
    int c = min(cnt[node], CAP);
    const unsigned* row = ep + (size_t)node * CAP;
    float disn = dis[node];
    float acc0 = 0.f, acc1 = 0.f, acc2 = 0.f, acc3 = 0.f;
    int k = 0;
    for (; k + 4 <= c; k += 4) {
        unsigned pA = row[k+0], pB = row[k+1], pC = row[k+2], pD = row[k+3];
        int sA = unpack_src(pA), sB = unpack_src(pB);
        int sC = unpack_src(pC), sD = unpack_src(pD);
        float wA = dis[sA] * unpack_ea(pA), wB = dis[sB] * unpack_ea(pB);
        float wC = dis[sC] * unpack_ea(pC), wD = dis[sD] * unpack_ea(pD);
        acc0 = fmaf(wA, El[x[sA] * 64 + d], acc0);
        acc1 = fmaf(wB, El[x[sB] * 64 + d], acc1);
        acc2 = fmaf(wC, El[x[sC] * 64 + d], acc2);
        acc3 = fmaf(wD, El[x[sD] * 64 + d], acc3);
    }
    for (; k < c; k++) {
        unsigned p = row[k];
        int s = unpack_src(p);
        acc0 = fmaf(dis[s] * unpack_ea(p), El[x[s] * 64 + d], acc0);
    }
    float v = ((acc0 + acc1) + (acc2 + acc3)) * disn
            + El[x[node] * 64 + d] * (disn * disn) + bias[d];
    A[(size_t)node * 64 + d] = fmaxf(v, 0.f);
}

// -------- dense: B(bf16) = A @ W  (A: [NN,64] fp32), W: [64,64] -------------------
__global__ __launch_bounds__(256) void k_matmul(const float* __restrict__ A,
                                                const float* __restrict__ W,
                                                unsigned short* __restrict__ B) {
    __shared__ float Wl[64 * 64];   // [k][d]
    __shared__ float Ar[16 * 64];   // [row][k]
    int t = threadIdx.x;
    for (int i = t * 4; i < 64 * 64; i += 256 * 4)
        *(float4*)&Wl[i] = *(const float4*)&W[i];
    int q   = t & 15;       // dim quad
    int sub = t >> 4;       // row slot 0..15
    int r0 = blockIdx.x * 64;
    for (int rg = 0; rg < 64; rg += 16) {
        __syncthreads();                       // covers Wl load on first iter
        {   // stage 16 rows (1024 floats, one float4 per thread)
            int idx = t * 4;
            int rr = idx >> 6, kk = idx & 63;
            int r = r0 + rg + rr;
            float4 a = (r < NN) ? *(const float4*)&A[(size_t)r * DD + kk]
                                : make_float4(0.f, 0.f, 0.f, 0.f);
            *(float4*)&Ar[idx] = a;
        }
        __syncthreads();
        int r = r0 + rg + sub;
        if (r < NN) {
            float4 acc = make_float4(0.f, 0.f, 0.f, 0.f);
            #pragma unroll
            for (int k = 0; k < 64; k++) {
                float a = Ar[sub * 64 + k];
                float4 w4 = *(float4*)&Wl[k * 64 + q * 4];
                acc.x = fmaf(a, w4.x, acc.x);
                acc.y = fmaf(a, w4.y, acc.y);
                acc.z = fmaf(a, w4.z, acc.z);
                acc.w = fmaf(a, w4.w, acc.w);
            }
            ushort4 o;
            o.x = f2bf(acc.x); o.y = f2bf(acc.y);
            o.z = f2bf(acc.z); o.w = f2bf(acc.w);
            *(ushort4*)&B[(size_t)r * DD + q * 4] = o;
        }
    }
}

// ------- SpMM gather: A[i] = sum_in dis[s]*ea*dis[i]*B[s] + B[i]*dis[i]^2 + bias ----
__global__ __launch_bounds__(256) void k_spmm(const int* __restrict__ cnt,
                                              const unsigned* __restrict__ ep,
                                              const float* __restrict__ dis,
                                              const unsigned short* __restrict__ B,
                                              const float* __restrict__ bias,
                                              float* __restrict__ A, int relu) {
    int node = blockIdx.x * 4 + (threadIdx.x >> 6);   // 1 wave per node
    int d = threadIdx.x & 63;
    if (node >= NN) return;
    int c = min(cnt[node], CAP);
    const unsigned* row = ep + (size_t)node * CAP;
    float disn = dis[node];
    float acc0 = 0.f, acc1 = 0.f, acc2 = 0.f, acc3 = 0.f;
    int k = 0;
    for (; k + 4 <= c; k += 4) {
        unsigned pA = row[k+0], pB = row[k+1], pC = row[k+2], pD = row[k+3];
        int sA = unpack_src(pA), sB = unpack_src(pB);
        int sC = unpack_src(pC), sD = unpack_src(pD);
        float wA = dis[sA] * unpack_ea(pA), wB = dis[sB] * unpack_ea(pB);
        float wC = dis[sC] * unpack_ea(pC), wD = dis[sD] * unpack_ea(pD);
        acc0 = fmaf(wA, bf2f(B[(size_t)sA * 64 + d]), acc0);
        acc1 = fmaf(wB, bf2f(B[(size_t)sB * 64 + d]), acc1);
        acc2 = fmaf(wC, bf2f(B[(size_t)sC * 64 + d]), acc2);
        acc3 = fmaf(wD, bf2f(B[(size_t)sD * 64 + d]), acc3);
    }
    for (; k < c; k++) {
        unsigned p = row[k];
        int s = unpack_src(p);
        acc0 = fmaf(dis[s] * unpack_ea(p), bf2f(B[(size_t)s * 64 + d]), acc0);
    }
    float v = ((acc0 + acc1) + (acc2 + acc3)) * disn
            + bf2f(B[(size_t)node * 64 + d]) * (disn * disn) + bias[d];
    if (relu) v = fmaxf(v, 0.f);
    A[(size_t)node * 64 + d] = v;
}

// ---------------- pooling (batch is sorted -> run-accumulate) ----------------
#define NODES_PER_GRP 64
__global__ void k_pool(const int* __restrict__ batch, const float* __restrict__ A,
                       float* __restrict__ pool, float* __restrict__ cnt) {
    int t = blockIdx.x * blockDim.x + threadIdx.x;
    int d = t & 63;
    int grp = t >> 6;
    int i0 = grp * NODES_PER_GRP;
    if (i0 >= NN) return;
    int i1 = min(i0 + NODES_PER_GRP, NN);
    int curg = batch[i0];
    float acc = 0.f, c = 0.f;
    for (int i = i0; i < i1; i++) {
        int g = batch[i];
        if (g != curg) {
            unsafeAtomicAdd(&pool[curg * 64 + d], acc);
            if (d == 0) unsafeAtomicAdd(&cnt[curg], c);
            acc = 0.f; c = 0.f; curg = g;
        }
        acc += A[(long long)i * 64 + d];
        c += 1.f;
    }
    unsafeAtomicAdd(&pool[curg * 64 + d], acc);
    if (d == 0) unsafeAtomicAdd(&cnt[curg], c);
}

// ---------------- mean + L2 normalize ----------------
__global__ void k_final(const float* __restrict__ pool, const float* __restrict__ cnt,
                        float* __restrict__ out) {
    int g = blockIdx.x;
    int d = threadIdx.x;                  // 64 threads = 1 wave
    float c = fmaxf(cnt[g], 1.0f);
    float m = pool[g * 64 + d] / c;
    float ss = m * m;
    #pragma unroll
    for (int o = 32; o > 0; o >>= 1) ss += __shfl_xor(ss, o);
    float nrm = sqrtf(ss);
    out[g * 64 + d] = m / fmaxf(nrm, 1e-12f);
}

extern "C" void kernel_launch(void* const* d_in, const int* in_sizes, int n_in,
                              void* d_out, int out_size, void* d_ws, size_t ws_size,
                              hipStream_t stream) {
    const int*   x    = (const int*)d_in[0];
    const int*   ei   = (const int*)d_in[1];
    const int*   src  = ei;
    const int*   dst  = ei + NE;
    const float* ea   = (const float*)d_in[2];
    const int*   batch= (const int*)d_in[3];
    const float* emb  = (const float*)d_in[4];
    const float* Ws[3] = {(const float*)d_in[5], (const float*)d_in[7], (const float*)d_in[9]};
    const float* bs[3] = {(const float*)d_in[6], (const float*)d_in[8], (const float*)d_in[10]};
    float* out = (float*)d_out;

    char* ws = (char*)d_ws;
    size_t off = 0;
    auto alloc = [&](size_t nb) -> void* {
        void* p = ws + off;
        off = (off + nb + 255) & ~(size_t)255;
        return p;
    };
    float*          dis    = (float*)alloc((size_t)NN * 4);
    int*            cntN   = (int*)  alloc((size_t)NN * 4);
    int*            bincur = (int*)  alloc((size_t)NB * 4);
    uint2*          binned = (uint2*)alloc((size_t)NB * BCAP * 8);
    unsigned*       ep     = (unsigned*)alloc((size_t)NN * CAP * 4); // {src, fp16 ea}
    float*          A      = (float*)alloc((size_t)NN * DD * 4);     // h (fp32)
    unsigned short* B      = (unsigned short*)alloc((size_t)NN * DD * 2); // hW (bf16)
    float*          E1     = (float*)alloc((size_t)VV * DD * 4);     // emb @ W1
    float*          pool   = (float*)alloc((size_t)GG * DD * 4);
    float*          cnt    = (float*)alloc((size_t)GG * 4);

    // ---- binned bucket build + degree/dis (once, reused by all 3 layers) ----
    hipMemsetAsync(bincur, 0, (size_t)NB * 4, stream);
    k_binA<<<(NE + 255) / 256, 256, 0, stream>>>(src, dst, ea, bincur, binned);
    k_binB<<<NB, 256, 0, stream>>>(bincur, binned, ep, cntN, dis);

    // ---- layer 1 (fused through the V=30 vocab: h1 = relu(S * E1[x] + b1)) ----
    k_emb_mm<<<1, 256, 0, stream>>>(emb, Ws[0], E1);
    k_layer1<<<(NN + 3) / 4, 256, 0, stream>>>(cntN, ep, dis, x, E1, bs[0], A);

    // ---- layers 2,3 ----
    for (int l = 1; l < 3; l++) {
        k_matmul<<<(NN + 63) / 64, 256, 0, stream>>>(A, Ws[l], B);
        k_spmm<<<(NN + 3) / 4, 256, 0, stream>>>(cntN, ep, dis, B, bs[l], A,
                                                 l < 2 ? 1 : 0);
    }

    // ---- pool + normalize ----
    hipMemsetAsync(pool, 0, (size_t)GG * DD * 4, stream);
    hipMemsetAsync(cnt, 0, (size_t)GG * 4, stream);
    int ngrp = (NN + NODES_PER_GRP - 1) / NODES_PER_GRP;
    k_pool<<<(ngrp * 64 + 255) / 256, 256, 0, stream>>>(batch, A, pool, cnt);
    k_final<<<GG, 64, 0, stream>>>(pool, cnt, out);
}

// Round 10
// 268.803 us; speedup vs baseline: 1.4553x; 1.4553x over previous
//
#include <hip/hip_runtime.h>
#include <hip/hip_fp16.h>

#define NN 50000     // nodes
#define NE 800000    // edges
#define DD 64        // embedding dim
#define GG 64        // graphs
#define VV 30        // node label vocab
#define CAP 48       // bucket capacity per node (in-degree ~ Poisson(16); P(>=48) ~ 1e-9)
#define PBLK 512     // blocks for fused layer3+pool
#define PCH ((NN + PBLK - 1) / PBLK)   // 98 contiguous nodes per block

// ---- bf16 helpers (RNE) ----
__device__ inline unsigned short f2bf(float f) {
    unsigned u = __float_as_uint(f);
    return (unsigned short)((u + 0x7FFF + ((u >> 16) & 1)) >> 16);
}
__device__ inline float bf2f(unsigned short s) {
    return __uint_as_float(((unsigned)s) << 16);
}
// ---- packed edge payload: src (lo16) | fp16(ea) (hi16) ----
__device__ inline unsigned pack_edge(int s, float ea) {
    return (unsigned)s | ((unsigned)__half_as_ushort(__float2half_rn(ea)) << 16);
}
__device__ inline int unpack_src(unsigned p) { return (int)(p & 0xFFFFu); }
__device__ inline float unpack_ea(unsigned p) {
    return __half2float(__ushort_as_half((unsigned short)(p >> 16)));
}

// ------- single edge pass: bucket fill  ep[dst][p] = pack(src, ea) ----------------
__global__ void k_fill_bucket(const int* __restrict__ src, const int* __restrict__ dst,
                              const float* __restrict__ ea,
                              int* __restrict__ cnt, unsigned* __restrict__ ep) {
    int e = blockIdx.x * blockDim.x + threadIdx.x;
    if (e < NE) {
        int t = dst[e];
        int p = atomicAdd(&cnt[t], 1);
        if (p < CAP) ep[(size_t)t * CAP + p] = pack_edge(src[e], ea[e]);
    }
}

// ------- per-node (16 lanes): deg = 1 + sum ea; dis = deg^-1/2 --------------------
__global__ void k_deg_dis(const int* __restrict__ cnt, const unsigned* __restrict__ ep,
                          float* __restrict__ dis) {
    int tid = blockIdx.x * blockDim.x + threadIdx.x;
    int node = tid >> 4, lane = tid & 15;
    if (node >= NN) return;
    int c = min(cnt[node], CAP);
    float s = 0.f;
    for (int k = lane; k < c; k += 16) s += unpack_ea(ep[(size_t)node * CAP + k]);
    #pragma unroll
    for (int o = 8; o > 0; o >>= 1) s += __shfl_xor(s, o, 16);
    if (lane == 0) {
        s += 1.0f;                        // self loop
        dis[node] = 1.0f / sqrtf(s);
    }
}

// ------- tiny dense: E1 = emb @ W1  (30x64 @ 64x64) -------------------------------
__global__ __launch_bounds__(256) void k_emb_mm(const float* __restrict__ emb,
                                                const float* __restrict__ W,
                                                float* __restrict__ E1) {
    int t = threadIdx.x;
    int d = t & 63;
    for (int v = t >> 6; v < VV; v += 4) {
        float acc = 0.f;
        #pragma unroll
        for (int k = 0; k < 64; k++) acc = fmaf(emb[v * 64 + k], W[k * 64 + d], acc);
        E1[v * 64 + d] = acc;
    }
}

// ------- layer 1 fused: h1 = relu( sum_in w*E1[x_s] + dis^2*E1[x_i] + b1 ) --------
__global__ __launch_bounds__(256) void k_layer1(const int* __restrict__ cnt,
                                                const unsigned* __restrict__ ep,
                                                const float* __restrict__ dis,
                                                const int* __restrict__ x,
                                                const float* __restrict__ E1,
                                                const float* __restrict__ bias,
                                                float* __restrict__ A) {
    __shared__ float El[VV * 64];
    int t = threadIdx.x;
    for (int i = t; i < VV * 64; i += 256) El[i] = E1[i];
    __syncthreads();
    int node = blockIdx.x * 4 + (t >> 6);   // 1 wave per node
    int d = t & 63;
    if (node >= NN) return;
    int c = min(cnt[node], CAP);
    const unsigned* row = ep + (size_t)node * CAP;
    float disn = dis[node];
    float acc0 = 0.f, acc1 = 0.f, acc2 = 0.f, acc3 = 0.f;
    int k = 0;
    for (; k + 4 <= c; k += 4) {
        unsigned pA = row[k+0], pB = row[k+1], pC = row[k+2], pD = row[k+3];
        int sA = unpack_src(pA), sB = unpack_src(pB);
        int sC = unpack_src(pC), sD = unpack_src(pD);
        float wA = dis[sA] * unpack_ea(pA), wB = dis[sB] * unpack_ea(pB);
        float wC = dis[sC] * unpack_ea(pC), wD = dis[sD] * unpack_ea(pD);
        acc0 = fmaf(wA, El[x[sA] * 64 + d], acc0);
        acc1 = fmaf(wB, El[x[sB] * 64 + d], acc1);
        acc2 = fmaf(wC, El[x[sC] * 64 + d], acc2);
        acc3 = fmaf(wD, El[x[sD] * 64 + d], acc3);
    }
    for (; k < c; k++) {
        unsigned p = row[k];
        int s = unpack_src(p);
        acc0 = fmaf(dis[s] * unpack_ea(p), El[x[s] * 64 + d], acc0);
    }
    float v = ((acc0 + acc1) + (acc2 + acc3)) * disn
            + El[x[node] * 64 + d] * (disn * disn) + bias[d];
    A[(size_t)node * 64 + d] = fmaxf(v, 0.f);
}

// -------- dense: B(bf16) = A @ W  (A: [NN,64] fp32), W: [64,64] -------------------
__global__ __launch_bounds__(256) void k_matmul(const float* __restrict__ A,
                                                const float* __restrict__ W,
                                                unsigned short* __restrict__ B) {
    __shared__ float Wl[64 * 64];   // [k][d]
    __shared__ float Ar[16 * 64];   // [row][k]
    int t = threadIdx.x;
    for (int i = t * 4; i < 64 * 64; i += 256 * 4)
        *(float4*)&Wl[i] = *(const float4*)&W[i];
    int q   = t & 15;       // dim quad
    int sub = t >> 4;       // row slot 0..15
    int r0 = blockIdx.x * 64;
    for (int rg = 0; rg < 64; rg += 16) {
        __syncthreads();                       // covers Wl load on first iter
        {   // stage 16 rows (1024 floats, one float4 per thread)
            int idx = t * 4;
            int rr = idx >> 6, kk = idx & 63;
            int r = r0 + rg + rr;
            float4 a = (r < NN) ? *(const float4*)&A[(size_t)r * DD + kk]
                                : make_float4(0.f, 0.f, 0.f, 0.f);
            *(float4*)&Ar[idx] = a;
        }
        __syncthreads();
        int r = r0 + rg + sub;
        if (r < NN) {
            float4 acc = make_float4(0.f, 0.f, 0.f, 0.f);
            #pragma unroll
            for (int k = 0; k < 64; k++) {
                float a = Ar[sub * 64 + k];
                float4 w4 = *(float4*)&Wl[k * 64 + q * 4];
                acc.x = fmaf(a, w4.x, acc.x);
                acc.y = fmaf(a, w4.y, acc.y);
                acc.z = fmaf(a, w4.z, acc.z);
                acc.w = fmaf(a, w4.w, acc.w);
            }
            ushort4 o;
            o.x = f2bf(acc.x); o.y = f2bf(acc.y);
            o.z = f2bf(acc.z); o.w = f2bf(acc.w);
            *(ushort4*)&B[(size_t)r * DD + q * 4] = o;
        }
    }
}

// ------- SpMM gather (layer 2): A[i] = relu(spmm_row + bias) ----------------------
__global__ __launch_bounds__(256) void k_spmm(const int* __restrict__ cnt,
                                              const unsigned* __restrict__ ep,
                                              const float* __restrict__ dis,
                                              const unsigned short* __restrict__ B,
                                              const float* __restrict__ bias,
                                              float* __restrict__ A) {
    int node = blockIdx.x * 4 + (threadIdx.x >> 6);   // 1 wave per node
    int d = threadIdx.x & 63;
    if (node >= NN) return;
    int c = min(cnt[node], CAP);
    const unsigned* row = ep + (size_t)node * CAP;
    float disn = dis[node];
    float acc0 = 0.f, acc1 = 0.f, acc2 = 0.f, acc3 = 0.f;
    int k = 0;
    for (; k + 4 <= c; k += 4) {
        unsigned pA = row[k+0], pB = row[k+1], pC = row[k+2], pD = row[k+3];
        int sA = unpack_src(pA), sB = unpack_src(pB);
        int sC = unpack_src(pC), sD = unpack_src(pD);
        float wA = dis[sA] * unpack_ea(pA), wB = dis[sB] * unpack_ea(pB);
        float wC = dis[sC] * unpack_ea(pC), wD = dis[sD] * unpack_ea(pD);
        acc0 = fmaf(wA, bf2f(B[(size_t)sA * 64 + d]), acc0);
        acc1 = fmaf(wB, bf2f(B[(size_t)sB * 64 + d]), acc1);
        acc2 = fmaf(wC, bf2f(B[(size_t)sC * 64 + d]), acc2);
        acc3 = fmaf(wD, bf2f(B[(size_t)sD * 64 + d]), acc3);
    }
    for (; k < c; k++) {
        unsigned p = row[k];
        int s = unpack_src(p);
        acc0 = fmaf(dis[s] * unpack_ea(p), bf2f(B[(size_t)s * 64 + d]), acc0);
    }
    float v = ((acc0 + acc1) + (acc2 + acc3)) * disn
            + bf2f(B[(size_t)node * 64 + d]) * (disn * disn) + bias[d];
    A[(size_t)node * 64 + d] = fmaxf(v, 0.f);
}

// ------- layer 3 + pool fused: LDS per-graph accumulation (batch sorted) ----------
__global__ __launch_bounds__(256) void k_spmm3_pool(const int* __restrict__ cnt,
                                                    const unsigned* __restrict__ ep,
                                                    const float* __restrict__ dis,
                                                    const unsigned short* __restrict__ B,
                                                    const float* __restrict__ bias,
                                                    const int* __restrict__ batch,
                                                    float* __restrict__ pool,
                                                    float* __restrict__ gcnt) {
    __shared__ float lpool[GG * DD];      // 16 KB
    __shared__ float lcnt[GG];
    int t = threadIdx.x;
    for (int i = t; i < GG * DD; i += 256) lpool[i] = 0.f;
    if (t < GG) lcnt[t] = 0.f;
    __syncthreads();
    int base = blockIdx.x * PCH;
    int end = min(base + PCH, NN);
    int d = t & 63;
    for (int node = base + (t >> 6); node < end; node += 4) {
        int c = min(cnt[node], CAP);
        const unsigned* row = ep + (size_t)node * CAP;
        float disn = dis[node];
        float acc0 = 0.f, acc1 = 0.f, acc2 = 0.f, acc3 = 0.f;
        int k = 0;
        for (; k + 4 <= c; k += 4) {
            unsigned pA = row[k+0], pB = row[k+1], pC = row[k+2], pD = row[k+3];
            int sA = unpack_src(pA), sB = unpack_src(pB);
            int sC = unpack_src(pC), sD = unpack_src(pD);
            float wA = dis[sA] * unpack_ea(pA), wB = dis[sB] * unpack_ea(pB);
            float wC = dis[sC] * unpack_ea(pC), wD = dis[sD] * unpack_ea(pD);
            acc0 = fmaf(wA, bf2f(B[(size_t)sA * 64 + d]), acc0);
            acc1 = fmaf(wB, bf2f(B[(size_t)sB * 64 + d]), acc1);
            acc2 = fmaf(wC, bf2f(B[(size_t)sC * 64 + d]), acc2);
            acc3 = fmaf(wD, bf2f(B[(size_t)sD * 64 + d]), acc3);
        }
        for (; k < c; k++) {
            unsigned p = row[k];
            int s = unpack_src(p);
            acc0 = fmaf(dis[s] * unpack_ea(p), bf2f(B[(size_t)s * 64 + d]), acc0);
        }
        float v = ((acc0 + acc1) + (acc2 + acc3)) * disn
                + bf2f(B[(size_t)node * 64 + d]) * (disn * disn) + bias[d];
        int g = batch[node];
        atomicAdd(&lpool[g * 64 + d], v);     // LDS atomic
        if (d == 0) atomicAdd(&lcnt[g], 1.f);
    }
    __syncthreads();
    for (int i = t; i < GG * DD; i += 256) {
        float v = lpool[i];
        if (v != 0.f) unsafeAtomicAdd(&pool[i], v);
    }
    if (t < GG) {
        float v = lcnt[t];
        if (v != 0.f) unsafeAtomicAdd(&gcnt[t], v);
    }
}

// ---------------- mean + L2 normalize ----------------
__global__ void k_final(const float* __restrict__ pool, const float* __restrict__ cnt,
                        float* __restrict__ out) {
    int g = blockIdx.x;
    int d = threadIdx.x;                  // 64 threads = 1 wave
    float c = fmaxf(cnt[g], 1.0f);
    float m = pool[g * 64 + d] / c;
    float ss = m * m;
    #pragma unroll
    for (int o = 32; o > 0; o >>= 1) ss += __shfl_xor(ss, o);
    float nrm = sqrtf(ss);
    out[g * 64 + d] = m / fmaxf(nrm, 1e-12f);
}

extern "C" void kernel_launch(void* const* d_in, const int* in_sizes, int n_in,
                              void* d_out, int out_size, void* d_ws, size_t ws_size,
                              hipStream_t stream) {
    const int*   x    = (const int*)d_in[0];
    const int*   ei   = (const int*)d_in[1];
    const int*   src  = ei;
    const int*   dst  = ei + NE;
    const float* ea   = (const float*)d_in[2];
    const int*   batch= (const int*)d_in[3];
    const float* emb  = (const float*)d_in[4];
    const float* Ws[3] = {(const float*)d_in[5], (const float*)d_in[7], (const float*)d_in[9]};
    const float* bs[3] = {(const float*)d_in[6], (const float*)d_in[8], (const float*)d_in[10]};
    float* out = (float*)d_out;

    char* ws = (char*)d_ws;
    size_t off = 0;
    auto alloc = [&](size_t nb) -> void* {
        void* p = ws + off;
        off = (off + nb + 255) & ~(size_t)255;
        return p;
    };
    float*          dis  = (float*)alloc((size_t)NN * 4);
    int*            cntN = (int*)  alloc((size_t)NN * 4);
    unsigned*       ep   = (unsigned*)alloc((size_t)NN * CAP * 4); // {src, fp16 ea}
    float*          A    = (float*)alloc((size_t)NN * DD * 4);     // h (fp32)
    unsigned short* B    = (unsigned short*)alloc((size_t)NN * DD * 2); // hW (bf16)
    float*          E1   = (float*)alloc((size_t)VV * DD * 4);     // emb @ W1
    float*          pool = (float*)alloc((size_t)GG * DD * 4);
    float*          cnt  = (float*)alloc((size_t)GG * 4);

    // ---- bucketed CSR + norm preprocessing (once, reused by all 3 layers) ----
    hipMemsetAsync(cntN, 0, (size_t)NN * 4, stream);
    k_fill_bucket<<<(NE + 255) / 256, 256, 0, stream>>>(src, dst, ea, cntN, ep);
    k_deg_dis<<<(NN * 16 + 255) / 256, 256, 0, stream>>>(cntN, ep, dis);

    // ---- layer 1 (fused through the V=30 vocab: h1 = relu(S * E1[x] + b1)) ----
    k_emb_mm<<<1, 256, 0, stream>>>(emb, Ws[0], E1);
    k_layer1<<<(NN + 3) / 4, 256, 0, stream>>>(cntN, ep, dis, x, E1, bs[0], A);

    // ---- layer 2 ----
    k_matmul<<<(NN + 63) / 64, 256, 0, stream>>>(A, Ws[1], B);
    k_spmm<<<(NN + 3) / 4, 256, 0, stream>>>(cntN, ep, dis, B, bs[1], A);

    // ---- layer 3 + pooling (fused) ----
    k_matmul<<<(NN + 63) / 64, 256, 0, stream>>>(A, Ws[2], B);
    hipMemsetAsync(pool, 0, (size_t)GG * DD * 4, stream);
    hipMemsetAsync(cnt, 0, (size_t)GG * 4, stream);
    k_spmm3_pool<<<PBLK, 256, 0, stream>>>(cntN, ep, dis, B, bs[2], batch, pool, cnt);

    // ---- normalize ----
    k_final<<<GG, 64, 0, stream>>>(pool, cnt, out);
}

// Round 11
// 197.392 us; speedup vs baseline: 1.9817x; 1.3618x over previous
//
#include <hip/hip_runtime.h>
#include <hip/hip_fp16.h>

#define NN 50000     // nodes
#define NE 800000    // edges
#define DD 64        // embedding dim
#define GG 64        // graphs
#define VV 30        // node label vocab
#define CAP 48       // bucket capacity per node (in-degree ~ Poisson(16); P(>=48) ~ 1e-9)
#define PBLK 512     // blocks for fused layer3+pool
#define PCH ((NN + PBLK - 1) / PBLK)   // 98 contiguous nodes per block

// ---- bf16 helpers (RNE) ----
__device__ inline unsigned short f2bf(float f) {
    unsigned u = __float_as_uint(f);
    return (unsigned short)((u + 0x7FFF + ((u >> 16) & 1)) >> 16);
}
__device__ inline float bf2f(unsigned short s) {
    return __uint_as_float(((unsigned)s) << 16);
}
// ---- packed edge payload: src (lo16) | fp16(ea) (hi16) ----
__device__ inline unsigned pack_edge(int s, float ea) {
    return (unsigned)s | ((unsigned)__half_as_ushort(__float2half_rn(ea)) << 16);
}
__device__ inline int unpack_src(unsigned p) { return (int)(p & 0xFFFFu); }
__device__ inline float unpack_ea(unsigned p) {
    return __half2float(__ushort_as_half((unsigned short)(p >> 16)));
}

// ------- single edge pass: bucket fill  ep[dst][p] = pack(src, ea) ----------------
__global__ void k_fill_bucket(const int* __restrict__ src, const int* __restrict__ dst,
                              const float* __restrict__ ea,
                              int* __restrict__ cnt, unsigned* __restrict__ ep) {
    int e = blockIdx.x * blockDim.x + threadIdx.x;
    if (e < NE) {
        int t = dst[e];
        int p = atomicAdd(&cnt[t], 1);
        if (p < CAP) ep[(size_t)t * CAP + p] = pack_edge(src[e], ea[e]);
    }
}

// ------- per-node (16 lanes): deg = 1 + sum ea; dis = deg^-1/2 --------------------
__global__ void k_deg_dis(const int* __restrict__ cnt, const unsigned* __restrict__ ep,
                          float* __restrict__ dis) {
    int tid = blockIdx.x * blockDim.x + threadIdx.x;
    int node = tid >> 4, lane = tid & 15;
    if (node >= NN) return;
    int c = min(cnt[node], CAP);
    float s = 0.f;
    for (int k = lane; k < c; k += 16) s += unpack_ea(ep[(size_t)node * CAP + k]);
    #pragma unroll
    for (int o = 8; o > 0; o >>= 1) s += __shfl_xor(s, o, 16);
    if (lane == 0) {
        s += 1.0f;                        // self loop
        dis[node] = 1.0f / sqrtf(s);
    }
}

// ------- tiny dense: E1 = emb @ W1  (30x64 @ 64x64) -------------------------------
__global__ __launch_bounds__(256) void k_emb_mm(const float* __restrict__ emb,
                                                const float* __restrict__ W,
                                                float* __restrict__ E1) {
    int t = threadIdx.x;
    int d = t & 63;
    for (int v = t >> 6; v < VV; v += 4) {
        float acc = 0.f;
        #pragma unroll
        for (int k = 0; k < 64; k++) acc = fmaf(emb[v * 64 + k], W[k * 64 + d], acc);
        E1[v * 64 + d] = acc;
    }
}

// ------- layer 1 fused: h1 = relu( sum_in w*E1[x_s] + dis^2*E1[x_i] + b1 ) --------
__global__ __launch_bounds__(256) void k_layer1(const int* __restrict__ cnt,
                                                const unsigned* __restrict__ ep,
                                                const float* __restrict__ dis,
                                                const int* __restrict__ x,
                                                const float* __restrict__ E1,
                                                const float* __restrict__ bias,
                                                float* __restrict__ A) {
    __shared__ float El[VV * 64];
    int t = threadIdx.x;
    for (int i = t; i < VV * 64; i += 256) El[i] = E1[i];
    __syncthreads();
    int node = blockIdx.x * 4 + (t >> 6);   // 1 wave per node
    int d = t & 63;
    if (node >= NN) return;
    int c = min(cnt[node], CAP);
    const unsigned* row = ep + (size_t)node * CAP;
    float disn = dis[node];
    float acc0 = 0.f, acc1 = 0.f, acc2 = 0.f, acc3 = 0.f;
    int k = 0;
    for (; k + 4 <= c; k += 4) {
        unsigned pA = row[k+0], pB = row[k+1], pC = row[k+2], pD = row[k+3];
        int sA = unpack_src(pA), sB = unpack_src(pB);
        int sC = unpack_src(pC), sD = unpack_src(pD);
        float wA = dis[sA] * unpack_ea(pA), wB = dis[sB] * unpack_ea(pB);
        float wC = dis[sC] * unpack_ea(pC), wD = dis[sD] * unpack_ea(pD);
        acc0 = fmaf(wA, El[x[sA] * 64 + d], acc0);
        acc1 = fmaf(wB, El[x[sB] * 64 + d], acc1);
        acc2 = fmaf(wC, El[x[sC] * 64 + d], acc2);
        acc3 = fmaf(wD, El[x[sD] * 64 + d], acc3);
    }
    for (; k < c; k++) {
        unsigned p = row[k];
        int s = unpack_src(p);
        acc0 = fmaf(dis[s] * unpack_ea(p), El[x[s] * 64 + d], acc0);
    }
    float v = ((acc0 + acc1) + (acc2 + acc3)) * disn
            + El[x[node] * 64 + d] * (disn * disn) + bias[d];
    A[(size_t)node * 64 + d] = fmaxf(v, 0.f);
}

// -------- dense: B(bf16) = A @ W  (A: [NN,64] fp32), W: [64,64] -------------------
__global__ __launch_bounds__(256) void k_matmul(const float* __restrict__ A,
                                                const float* __restrict__ W,
                                                unsigned short* __restrict__ B) {
    __shared__ float Wl[64 * 64];   // [k][d]
    __shared__ float Ar[16 * 64];   // [row][k]
    int t = threadIdx.x;
    for (int i = t * 4; i < 64 * 64; i += 256 * 4)
        *(float4*)&Wl[i] = *(const float4*)&W[i];
    int q   = t & 15;       // dim quad
    int sub = t >> 4;       // row slot 0..15
    int r0 = blockIdx.x * 64;
    for (int rg = 0; rg < 64; rg += 16) {
        __syncthreads();                       // covers Wl load on first iter
        {   // stage 16 rows (1024 floats, one float4 per thread)
            int idx = t * 4;
            int rr = idx >> 6, kk = idx & 63;
            int r = r0 + rg + rr;
            float4 a = (r < NN) ? *(const float4*)&A[(size_t)r * DD + kk]
                                : make_float4(0.f, 0.f, 0.f, 0.f);
            *(float4*)&Ar[idx] = a;
        }
        __syncthreads();
        int r = r0 + rg + sub;
        if (r < NN) {
            float4 acc = make_float4(0.f, 0.f, 0.f, 0.f);
            #pragma unroll
            for (int k = 0; k < 64; k++) {
                float a = Ar[sub * 64 + k];
                float4 w4 = *(float4*)&Wl[k * 64 + q * 4];
                acc.x = fmaf(a, w4.x, acc.x);
                acc.y = fmaf(a, w4.y, acc.y);
                acc.z = fmaf(a, w4.z, acc.z);
                acc.w = fmaf(a, w4.w, acc.w);
            }
            ushort4 o;
            o.x = f2bf(acc.x); o.y = f2bf(acc.y);
            o.z = f2bf(acc.z); o.w = f2bf(acc.w);
            *(ushort4*)&B[(size_t)r * DD + q * 4] = o;
        }
    }
}

// ------- SpMM gather (layer 2): A2(bf16) = relu(spmm_row + bias) ------------------
__global__ __launch_bounds__(256) void k_spmm2(const int* __restrict__ cnt,
                                               const unsigned* __restrict__ ep,
                                               const float* __restrict__ dis,
                                               const unsigned short* __restrict__ B,
                                               const float* __restrict__ bias,
                                               unsigned short* __restrict__ A2) {
    int node = blockIdx.x * 4 + (threadIdx.x >> 6);   // 1 wave per node
    int d = threadIdx.x & 63;
    if (node >= NN) return;
    int c = min(cnt[node], CAP);
    const unsigned* row = ep + (size_t)node * CAP;
    float disn = dis[node];
    float acc0 = 0.f, acc1 = 0.f, acc2 = 0.f, acc3 = 0.f;
    int k = 0;
    for (; k + 4 <= c; k += 4) {
        unsigned pA = row[k+0], pB = row[k+1], pC = row[k+2], pD = row[k+3];
        int sA = unpack_src(pA), sB = unpack_src(pB);
        int sC = unpack_src(pC), sD = unpack_src(pD);
        float wA = dis[sA] * unpack_ea(pA), wB = dis[sB] * unpack_ea(pB);
        float wC = dis[sC] * unpack_ea(pC), wD = dis[sD] * unpack_ea(pD);
        acc0 = fmaf(wA, bf2f(B[(size_t)sA * 64 + d]), acc0);
        acc1 = fmaf(wB, bf2f(B[(size_t)sB * 64 + d]), acc1);
        acc2 = fmaf(wC, bf2f(B[(size_t)sC * 64 + d]), acc2);
        acc3 = fmaf(wD, bf2f(B[(size_t)sD * 64 + d]), acc3);
    }
    for (; k < c; k++) {
        unsigned p = row[k];
        int s = unpack_src(p);
        acc0 = fmaf(dis[s] * unpack_ea(p), bf2f(B[(size_t)s * 64 + d]), acc0);
    }
    float v = ((acc0 + acc1) + (acc2 + acc3)) * disn
            + bf2f(B[(size_t)node * 64 + d]) * (disn * disn) + bias[d];
    A2[(size_t)node * 64 + d] = f2bf(fmaxf(v, 0.f));
}

// ------- layer 3 aggregate + pool fused (NO W3 — pooled then W3 by linearity) -----
__global__ __launch_bounds__(1024) void k_spmm3_pool(const int* __restrict__ cnt,
                                                     const unsigned* __restrict__ ep,
                                                     const float* __restrict__ dis,
                                                     const unsigned short* __restrict__ A2,
                                                     const int* __restrict__ batch,
                                                     float* __restrict__ pool,
                                                     float* __restrict__ gcnt) {
    __shared__ float lpool[GG * DD];      // 16 KB
    __shared__ float lcnt[GG];
    int t = threadIdx.x;
    for (int i = t; i < GG * DD; i += 1024) lpool[i] = 0.f;
    if (t < GG) lcnt[t] = 0.f;
    __syncthreads();
    int base = blockIdx.x * PCH;
    int end = min(base + PCH, NN);
    int d = t & 63;
    for (int node = base + (t >> 6); node < end; node += 16) {   // 16 waves
        int c = min(cnt[node], CAP);
        const unsigned* row = ep + (size_t)node * CAP;
        float disn = dis[node];
        float acc0 = 0.f, acc1 = 0.f, acc2 = 0.f, acc3 = 0.f;
        int k = 0;
        for (; k + 4 <= c; k += 4) {
            unsigned pA = row[k+0], pB = row[k+1], pC = row[k+2], pD = row[k+3];
            int sA = unpack_src(pA), sB = unpack_src(pB);
            int sC = unpack_src(pC), sD = unpack_src(pD);
            float wA = dis[sA] * unpack_ea(pA), wB = dis[sB] * unpack_ea(pB);
            float wC = dis[sC] * unpack_ea(pC), wD = dis[sD] * unpack_ea(pD);
            acc0 = fmaf(wA, bf2f(A2[(size_t)sA * 64 + d]), acc0);
            acc1 = fmaf(wB, bf2f(A2[(size_t)sB * 64 + d]), acc1);
            acc2 = fmaf(wC, bf2f(A2[(size_t)sC * 64 + d]), acc2);
            acc3 = fmaf(wD, bf2f(A2[(size_t)sD * 64 + d]), acc3);
        }
        for (; k < c; k++) {
            unsigned p = row[k];
            int s = unpack_src(p);
            acc0 = fmaf(dis[s] * unpack_ea(p), bf2f(A2[(size_t)s * 64 + d]), acc0);
        }
        float v = ((acc0 + acc1) + (acc2 + acc3)) * disn
                + bf2f(A2[(size_t)node * 64 + d]) * (disn * disn);
        int g = batch[node];
        atomicAdd(&lpool[g * 64 + d], v);     // LDS atomic
        if (d == 0) atomicAdd(&lcnt[g], 1.f);
    }
    __syncthreads();
    for (int i = t; i < GG * DD; i += 1024) {
        float v = lpool[i];
        if (v != 0.f) unsafeAtomicAdd(&pool[i], v);
    }
    if (t < GG) {
        float v = lcnt[t];
        if (v != 0.f) unsafeAtomicAdd(&gcnt[t], v);
    }
}

// ------- final: mean -> @W3 + b3 -> L2 normalize  (G=64 rows, 1 block) ------------
__global__ __launch_bounds__(1024) void k_final_mm(const float* __restrict__ pool,
                                                   const float* __restrict__ gcnt,
                                                   const float* __restrict__ W3,
                                                   const float* __restrict__ b3,
                                                   float* __restrict__ out) {
    __shared__ float Wl[DD * DD];     // 16 KB [k][d]
    __shared__ float Ml[GG * DD];     // 16 KB mean rows
    int t = threadIdx.x;
    for (int i = t; i < DD * DD; i += 1024) Wl[i] = W3[i];
    for (int i = t; i < GG * DD; i += 1024) {
        int g = i >> 6;
        Ml[i] = pool[i] / fmaxf(gcnt[g], 1.0f);
    }
    __syncthreads();
    int w = t >> 6, d = t & 63;       // 16 waves, lane = output dim
    for (int g = w; g < GG; g += 16) {
        float acc = b3[d];
        #pragma unroll
        for (int k = 0; k < 64; k++) acc = fmaf(Ml[g * 64 + k], Wl[k * 64 + d], acc);
        float ss = acc * acc;
        #pragma unroll
        for (int o = 32; o > 0; o >>= 1) ss += __shfl_xor(ss, o);
        out[g * 64 + d] = acc / fmaxf(sqrtf(ss), 1e-12f);
    }
}

extern "C" void kernel_launch(void* const* d_in, const int* in_sizes, int n_in,
                              void* d_out, int out_size, void* d_ws, size_t ws_size,
                              hipStream_t stream) {
    const int*   x    = (const int*)d_in[0];
    const int*   ei   = (const int*)d_in[1];
    const int*   src  = ei;
    const int*   dst  = ei + NE;
    const float* ea   = (const float*)d_in[2];
    const int*   batch= (const int*)d_in[3];
    const float* emb  = (const float*)d_in[4];
    const float* Ws[3] = {(const float*)d_in[5], (const float*)d_in[7], (const float*)d_in[9]};
    const float* bs[3] = {(const float*)d_in[6], (const float*)d_in[8], (const float*)d_in[10]};
    float* out = (float*)d_out;

    char* ws = (char*)d_ws;
    size_t off = 0;
    auto alloc = [&](size_t nb) -> void* {
        void* p = ws + off;
        off = (off + nb + 255) & ~(size_t)255;
        return p;
    };
    float*          dis  = (float*)alloc((size_t)NN * 4);
    int*            cntN = (int*)  alloc((size_t)NN * 4);
    unsigned*       ep   = (unsigned*)alloc((size_t)NN * CAP * 4); // {src, fp16 ea}
    float*          A    = (float*)alloc((size_t)NN * DD * 4);     // h1 (fp32)
    unsigned short* B    = (unsigned short*)alloc((size_t)NN * DD * 2); // h1@W2 (bf16)
    unsigned short* A2   = (unsigned short*)alloc((size_t)NN * DD * 2); // h2 (bf16)
    float*          E1   = (float*)alloc((size_t)VV * DD * 4);     // emb @ W1
    float*          pool = (float*)alloc((size_t)GG * DD * 4);
    float*          cnt  = (float*)alloc((size_t)GG * 4);

    // ---- bucketed CSR + norm preprocessing (once, reused by all 3 layers) ----
    hipMemsetAsync(cntN, 0, (size_t)NN * 4, stream);
    k_fill_bucket<<<(NE + 255) / 256, 256, 0, stream>>>(src, dst, ea, cntN, ep);
    k_deg_dis<<<(NN * 16 + 255) / 256, 256, 0, stream>>>(cntN, ep, dis);

    // ---- layer 1 (fused through the V=30 vocab: h1 = relu(S * E1[x] + b1)) ----
    k_emb_mm<<<1, 256, 0, stream>>>(emb, Ws[0], E1);
    k_layer1<<<(NN + 3) / 4, 256, 0, stream>>>(cntN, ep, dis, x, E1, bs[0], A);

    // ---- layer 2 ----
    k_matmul<<<(NN + 63) / 64, 256, 0, stream>>>(A, Ws[1], B);
    k_spmm2<<<(NN + 3) / 4, 256, 0, stream>>>(cntN, ep, dis, B, bs[1], A2);

    // ---- layer 3 aggregate + pooling (fused; W3 applied after pooling) ----
    hipMemsetAsync(pool, 0, (size_t)GG * DD * 4, stream);
    hipMemsetAsync(cnt, 0, (size_t)GG * 4, stream);
    k_spmm3_pool<<<PBLK, 1024, 0, stream>>>(cntN, ep, dis, A2, batch, pool, cnt);

    // ---- mean -> W3 -> normalize ----
    k_final_mm<<<1, 1024, 0, stream>>>(pool, cnt, Ws[2], bs[2], out);
}

// Round 12
// 185.239 us; speedup vs baseline: 2.1118x; 1.0656x over previous
//
#include <hip/hip_runtime.h>
#include <hip/hip_fp16.h>

#define NN 50000     // nodes
#define NE 800000    // edges
#define DD 64        // embedding dim
#define GG 64        // graphs
#define VV 30        // node label vocab
#define CAP 48       // bucket capacity per node (in-degree ~ Poisson(16); P(>=48) ~ 1e-9)
#define PBLK 512     // blocks for fused layer3+pool
#define PCH ((NN + PBLK - 1) / PBLK)   // 98 contiguous nodes per block

// ---- bf16 helpers (RNE) ----
__device__ inline unsigned short f2bf(float f) {
    unsigned u = __float_as_uint(f);
    return (unsigned short)((u + 0x7FFF + ((u >> 16) & 1)) >> 16);
}
__device__ inline float bf2f(unsigned short s) {
    return __uint_as_float(((unsigned)s) << 16);
}
// ---- packed edge payload: src (lo16) | fp16(ea) (hi16) ----
__device__ inline unsigned pack_edge(int s, float ea) {
    return (unsigned)s | ((unsigned)__half_as_ushort(__float2half_rn(ea)) << 16);
}
__device__ inline int unpack_src(unsigned p) { return (int)(p & 0xFFFFu); }
__device__ inline float unpack_ea(unsigned p) {
    return __half2float(__ushort_as_half((unsigned short)(p >> 16)));
}

// ------- single edge pass: bucket fill  ep[dst][p] = pack(src, ea) ----------------
__global__ void k_fill_bucket(const int* __restrict__ src, const int* __restrict__ dst,
                              const float* __restrict__ ea,
                              int* __restrict__ cnt, unsigned* __restrict__ ep) {
    int e = blockIdx.x * blockDim.x + threadIdx.x;
    if (e < NE) {
        int t = dst[e];
        int p = atomicAdd(&cnt[t], 1);
        if (p < CAP) ep[(size_t)t * CAP + p] = pack_edge(src[e], ea[e]);
    }
}

// ------- per-node (16 lanes): deg = 1 + sum ea; dis = deg^-1/2 --------------------
__global__ void k_deg_dis(const int* __restrict__ cnt, const unsigned* __restrict__ ep,
                          float* __restrict__ dis) {
    int tid = blockIdx.x * blockDim.x + threadIdx.x;
    int node = tid >> 4, lane = tid & 15;
    if (node >= NN) return;
    int c = min(cnt[node], CAP);
    float s = 0.f;
    for (int k = lane; k < c; k += 16) s += unpack_ea(ep[(size_t)node * CAP + k]);
    #pragma unroll
    for (int o = 8; o > 0; o >>= 1) s += __shfl_xor(s, o, 16);
    if (lane == 0) {
        s += 1.0f;                        // self loop
        dis[node] = 1.0f / sqrtf(s);
    }
}

// ------- tiny dense: E1 = emb @ W1  (30x64 @ 64x64) -------------------------------
__global__ __launch_bounds__(256) void k_emb_mm(const float* __restrict__ emb,
                                                const float* __restrict__ W,
                                                float* __restrict__ E1) {
    int t = threadIdx.x;
    int d = t & 63;
    for (int v = t >> 6; v < VV; v += 4) {
        float acc = 0.f;
        #pragma unroll
        for (int k = 0; k < 64; k++) acc = fmaf(emb[v * 64 + k], W[k * 64 + d], acc);
        E1[v * 64 + d] = acc;
    }
}

// ------- layer 1 fused: h1 = relu( sum_in w*E1[x_s] + dis^2*E1[x_i] + b1 ) --------
// wave preloads payload row (lane k = edge k), shfl-broadcasts -> independent gathers
__global__ __launch_bounds__(256) void k_layer1(const int* __restrict__ cnt,
                                                const unsigned* __restrict__ ep,
                                                const float* __restrict__ dis,
                                                const int* __restrict__ x,
                                                const float* __restrict__ E1,
                                                const float* __restrict__ bias,
                                                unsigned short* __restrict__ A1) {
    __shared__ float El[VV * 64];
    int t = threadIdx.x;
    for (int i = t; i < VV * 64; i += 256) El[i] = E1[i];
    __syncthreads();
    int node = blockIdx.x * 4 + (t >> 6);   // 1 wave per node
    int d = t & 63;
    if (node >= NN) return;
    int c = min(cnt[node], CAP);
    const unsigned* row = ep + (size_t)node * CAP;
    unsigned pay = (d < c) ? row[d] : 0u;   // pad edges: ea=0 -> w=0
    float disn = dis[node];
    float a0 = 0.f, a1 = 0.f, a2 = 0.f, a3 = 0.f;
    int iters = (c + 7) >> 3;
    for (int it = 0; it < iters; ++it) {
        int k0 = it << 3;
        unsigned p0 = __shfl(pay, k0+0), p1 = __shfl(pay, k0+1);
        unsigned p2 = __shfl(pay, k0+2), p3 = __shfl(pay, k0+3);
        unsigned p4 = __shfl(pay, k0+4), p5 = __shfl(pay, k0+5);
        unsigned p6 = __shfl(pay, k0+6), p7 = __shfl(pay, k0+7);
        int s0 = unpack_src(p0), s1 = unpack_src(p1), s2 = unpack_src(p2), s3 = unpack_src(p3);
        int s4 = unpack_src(p4), s5 = unpack_src(p5), s6 = unpack_src(p6), s7 = unpack_src(p7);
        int x0 = x[s0], x1 = x[s1], x2 = x[s2], x3 = x[s3];
        int x4 = x[s4], x5 = x[s5], x6 = x[s6], x7 = x[s7];
        float w0 = dis[s0] * unpack_ea(p0), w1 = dis[s1] * unpack_ea(p1);
        float w2 = dis[s2] * unpack_ea(p2), w3 = dis[s3] * unpack_ea(p3);
        float w4 = dis[s4] * unpack_ea(p4), w5 = dis[s5] * unpack_ea(p5);
        float w6 = dis[s6] * unpack_ea(p6), w7 = dis[s7] * unpack_ea(p7);
        a0 = fmaf(w0, El[x0 * 64 + d], a0); a1 = fmaf(w1, El[x1 * 64 + d], a1);
        a2 = fmaf(w2, El[x2 * 64 + d], a2); a3 = fmaf(w3, El[x3 * 64 + d], a3);
        a0 = fmaf(w4, El[x4 * 64 + d], a0); a1 = fmaf(w5, El[x5 * 64 + d], a1);
        a2 = fmaf(w6, El[x6 * 64 + d], a2); a3 = fmaf(w7, El[x7 * 64 + d], a3);
    }
    float v = ((a0 + a1) + (a2 + a3)) * disn
            + El[x[node] * 64 + d] * (disn * disn) + bias[d];
    A1[(size_t)node * 64 + d] = f2bf(fmaxf(v, 0.f));
}

// -------- dense: B(bf16) = A(bf16) @ W  , W: [64,64] fp32 -------------------------
__global__ __launch_bounds__(256) void k_matmul(const unsigned short* __restrict__ A,
                                                const float* __restrict__ W,
                                                unsigned short* __restrict__ B) {
    __shared__ float Wl[64 * 64];   // [k][d]
    __shared__ float Ar[16 * 64];   // [row][k]
    int t = threadIdx.x;
    for (int i = t * 4; i < 64 * 64; i += 256 * 4)
        *(float4*)&Wl[i] = *(const float4*)&W[i];
    int q   = t & 15;       // dim quad
    int sub = t >> 4;       // row slot 0..15
    int r0 = blockIdx.x * 64;
    for (int rg = 0; rg < 64; rg += 16) {
        __syncthreads();                       // covers Wl load on first iter
        {   // stage 16 rows (1024 elems, one ushort4 per thread)
            int idx = t * 4;
            int rr = idx >> 6, kk = idx & 63;
            int r = r0 + rg + rr;
            float4 a = make_float4(0.f, 0.f, 0.f, 0.f);
            if (r < NN) {
                ushort4 u = *(const ushort4*)&A[(size_t)r * DD + kk];
                a = make_float4(bf2f(u.x), bf2f(u.y), bf2f(u.z), bf2f(u.w));
            }
            *(float4*)&Ar[idx] = a;
        }
        __syncthreads();
        int r = r0 + rg + sub;
        if (r < NN) {
            float4 acc = make_float4(0.f, 0.f, 0.f, 0.f);
            #pragma unroll
            for (int k = 0; k < 64; k++) {
                float a = Ar[sub * 64 + k];
                float4 w4 = *(float4*)&Wl[k * 64 + q * 4];
                acc.x = fmaf(a, w4.x, acc.x);
                acc.y = fmaf(a, w4.y, acc.y);
                acc.z = fmaf(a, w4.z, acc.z);
                acc.w = fmaf(a, w4.w, acc.w);
            }
            ushort4 o;
            o.x = f2bf(acc.x); o.y = f2bf(acc.y);
            o.z = f2bf(acc.z); o.w = f2bf(acc.w);
            *(ushort4*)&B[(size_t)r * DD + q * 4] = o;
        }
    }
}

// ------- SpMM gather (layer 2): A2(bf16) = relu(spmm_row + bias) ------------------
__global__ __launch_bounds__(256) void k_spmm2(const int* __restrict__ cnt,
                                               const unsigned* __restrict__ ep,
                                               const float* __restrict__ dis,
                                               const unsigned short* __restrict__ B,
                                               const float* __restrict__ bias,
                                               unsigned short* __restrict__ A2) {
    int node = blockIdx.x * 4 + (threadIdx.x >> 6);   // 1 wave per node
    int d = threadIdx.x & 63;
    if (node >= NN) return;
    int c = min(cnt[node], CAP);
    const unsigned* row = ep + (size_t)node * CAP;
    unsigned pay = (d < c) ? row[d] : 0u;
    float disn = dis[node];
    float a0 = 0.f, a1 = 0.f, a2 = 0.f, a3 = 0.f;
    int iters = (c + 7) >> 3;
    for (int it = 0; it < iters; ++it) {
        int k0 = it << 3;
        unsigned p0 = __shfl(pay, k0+0), p1 = __shfl(pay, k0+1);
        unsigned p2 = __shfl(pay, k0+2), p3 = __shfl(pay, k0+3);
        unsigned p4 = __shfl(pay, k0+4), p5 = __shfl(pay, k0+5);
        unsigned p6 = __shfl(pay, k0+6), p7 = __shfl(pay, k0+7);
        int s0 = unpack_src(p0), s1 = unpack_src(p1), s2 = unpack_src(p2), s3 = unpack_src(p3);
        int s4 = unpack_src(p4), s5 = unpack_src(p5), s6 = unpack_src(p6), s7 = unpack_src(p7);
        float g0 = bf2f(B[(size_t)s0 * 64 + d]), g1 = bf2f(B[(size_t)s1 * 64 + d]);
        float g2 = bf2f(B[(size_t)s2 * 64 + d]), g3 = bf2f(B[(size_t)s3 * 64 + d]);
        float g4 = bf2f(B[(size_t)s4 * 64 + d]), g5 = bf2f(B[(size_t)s5 * 64 + d]);
        float g6 = bf2f(B[(size_t)s6 * 64 + d]), g7 = bf2f(B[(size_t)s7 * 64 + d]);
        float w0 = dis[s0] * unpack_ea(p0), w1 = dis[s1] * unpack_ea(p1);
        float w2 = dis[s2] * unpack_ea(p2), w3 = dis[s3] * unpack_ea(p3);
        float w4 = dis[s4] * unpack_ea(p4), w5 = dis[s5] * unpack_ea(p5);
        float w6 = dis[s6] * unpack_ea(p6), w7 = dis[s7] * unpack_ea(p7);
        a0 = fmaf(w0, g0, a0); a1 = fmaf(w1, g1, a1);
        a2 = fmaf(w2, g2, a2); a3 = fmaf(w3, g3, a3);
        a0 = fmaf(w4, g4, a0); a1 = fmaf(w5, g5, a1);
        a2 = fmaf(w6, g6, a2); a3 = fmaf(w7, g7, a3);
    }
    float v = ((a0 + a1) + (a2 + a3)) * disn
            + bf2f(B[(size_t)node * 64 + d]) * (disn * disn) + bias[d];
    A2[(size_t)node * 64 + d] = f2bf(fmaxf(v, 0.f));
}

// ------- layer 3 aggregate + pool fused (NO W3 — applied after pooling) -----------
__global__ __launch_bounds__(1024) void k_spmm3_pool(const int* __restrict__ cnt,
                                                     const unsigned* __restrict__ ep,
                                                     const float* __restrict__ dis,
                                                     const unsigned short* __restrict__ A2,
                                                     const int* __restrict__ batch,
                                                     float* __restrict__ pool,
                                                     float* __restrict__ gcnt) {
    __shared__ float lpool[GG * DD];      // 16 KB
    __shared__ float lcnt[GG];
    int t = threadIdx.x;
    for (int i = t; i < GG * DD; i += 1024) lpool[i] = 0.f;
    if (t < GG) lcnt[t] = 0.f;
    __syncthreads();
    int base = blockIdx.x * PCH;
    int end = min(base + PCH, NN);
    int d = t & 63;
    for (int node = base + (t >> 6); node < end; node += 16) {   // 16 waves
        int c = min(cnt[node], CAP);
        const unsigned* row = ep + (size_t)node * CAP;
        unsigned pay = (d < c) ? row[d] : 0u;
        float disn = dis[node];
        float a0 = 0.f, a1 = 0.f, a2 = 0.f, a3 = 0.f;
        int iters = (c + 7) >> 3;
        for (int it = 0; it < iters; ++it) {
            int k0 = it << 3;
            unsigned p0 = __shfl(pay, k0+0), p1 = __shfl(pay, k0+1);
            unsigned p2 = __shfl(pay, k0+2), p3 = __shfl(pay, k0+3);
            unsigned p4 = __shfl(pay, k0+4), p5 = __shfl(pay, k0+5);
            unsigned p6 = __shfl(pay, k0+6), p7 = __shfl(pay, k0+7);
            int s0 = unpack_src(p0), s1 = unpack_src(p1), s2 = unpack_src(p2), s3 = unpack_src(p3);
            int s4 = unpack_src(p4), s5 = unpack_src(p5), s6 = unpack_src(p6), s7 = unpack_src(p7);
            float g0 = bf2f(A2[(size_t)s0 * 64 + d]), g1 = bf2f(A2[(size_t)s1 * 64 + d]);
            float g2 = bf2f(A2[(size_t)s2 * 64 + d]), g3 = bf2f(A2[(size_t)s3 * 64 + d]);
            float g4 = bf2f(A2[(size_t)s4 * 64 + d]), g5 = bf2f(A2[(size_t)s5 * 64 + d]);
            float g6 = bf2f(A2[(size_t)s6 * 64 + d]), g7 = bf2f(A2[(size_t)s7 * 64 + d]);
            float w0 = dis[s0] * unpack_ea(p0), w1 = dis[s1] * unpack_ea(p1);
            float w2 = dis[s2] * unpack_ea(p2), w3 = dis[s3] * unpack_ea(p3);
            float w4 = dis[s4] * unpack_ea(p4), w5 = dis[s5] * unpack_ea(p5);
            float w6 = dis[s6] * unpack_ea(p6), w7 = dis[s7] * unpack_ea(p7);
            a0 = fmaf(w0, g0, a0); a1 = fmaf(w1, g1, a1);
            a2 = fmaf(w2, g2, a2); a3 = fmaf(w3, g3, a3);
            a0 = fmaf(w4, g4, a0); a1 = fmaf(w5, g5, a1);
            a2 = fmaf(w6, g6, a2); a3 = fmaf(w7, g7, a3);
        }
        float v = ((a0 + a1) + (a2 + a3)) * disn
                + bf2f(A2[(size_t)node * 64 + d]) * (disn * disn);
        int g = batch[node];
        atomicAdd(&lpool[g * 64 + d], v);     // LDS atomic
        if (d == 0) atomicAdd(&lcnt[g], 1.f);
    }
    __syncthreads();
    for (int i = t; i < GG * DD; i += 1024) {
        float v = lpool[i];
        if (v != 0.f) unsafeAtomicAdd(&pool[i], v);
    }
    if (t < GG) {
        float v = lcnt[t];
        if (v != 0.f) unsafeAtomicAdd(&gcnt[t], v);
    }
}

// ------- final: mean -> @W3 + b3 -> L2 normalize  (G=64 rows, 1 block) ------------
__global__ __launch_bounds__(1024) void k_final_mm(const float* __restrict__ pool,
                                                   const float* __restrict__ gcnt,
                                                   const float* __restrict__ W3,
                                                   const float* __restrict__ b3,
                                                   float* __restrict__ out) {
    __shared__ float Wl[DD * DD];     // 16 KB [k][d]
    __shared__ float Ml[GG * DD];     // 16 KB mean rows
    int t = threadIdx.x;
    for (int i = t; i < DD * DD; i += 1024) Wl[i] = W3[i];
    for (int i = t; i < GG * DD; i += 1024) {
        int g = i >> 6;
        Ml[i] = pool[i] / fmaxf(gcnt[g], 1.0f);
    }
    __syncthreads();
    int w = t >> 6, d = t & 63;       // 16 waves, lane = output dim
    for (int g = w; g < GG; g += 16) {
        float acc = b3[d];
        #pragma unroll
        for (int k = 0; k < 64; k++) acc = fmaf(Ml[g * 64 + k], Wl[k * 64 + d], acc);
        float ss = acc * acc;
        #pragma unroll
        for (int o = 32; o > 0; o >>= 1) ss += __shfl_xor(ss, o);
        out[g * 64 + d] = acc / fmaxf(sqrtf(ss), 1e-12f);
    }
}

extern "C" void kernel_launch(void* const* d_in, const int* in_sizes, int n_in,
                              void* d_out, int out_size, void* d_ws, size_t ws_size,
                              hipStream_t stream) {
    const int*   x    = (const int*)d_in[0];
    const int*   ei   = (const int*)d_in[1];
    const int*   src  = ei;
    const int*   dst  = ei + NE;
    const float* ea   = (const float*)d_in[2];
    const int*   batch= (const int*)d_in[3];
    const float* emb  = (const float*)d_in[4];
    const float* Ws[3] = {(const float*)d_in[5], (const float*)d_in[7], (const float*)d_in[9]};
    const float* bs[3] = {(const float*)d_in[6], (const float*)d_in[8], (const float*)d_in[10]};
    float* out = (float*)d_out;

    char* ws = (char*)d_ws;
    size_t off = 0;
    auto alloc = [&](size_t nb) -> void* {
        void* p = ws + off;
        off = (off + nb + 255) & ~(size_t)255;
        return p;
    };
    float*          dis  = (float*)alloc((size_t)NN * 4);
    int*            cntN = (int*)  alloc((size_t)NN * 4);
    unsigned*       ep   = (unsigned*)alloc((size_t)NN * CAP * 4); // {src, fp16 ea}
    unsigned short* A1   = (unsigned short*)alloc((size_t)NN * DD * 2); // h1 (bf16)
    unsigned short* B    = (unsigned short*)alloc((size_t)NN * DD * 2); // h1@W2 (bf16)
    unsigned short* A2   = (unsigned short*)alloc((size_t)NN * DD * 2); // h2 (bf16)
    float*          E1   = (float*)alloc((size_t)VV * DD * 4);     // emb @ W1
    float*          pool = (float*)alloc((size_t)GG * DD * 4);
    float*          cnt  = (float*)alloc((size_t)GG * 4);

    // ---- bucketed CSR + norm preprocessing (once, reused by all 3 layers) ----
    hipMemsetAsync(cntN, 0, (size_t)NN * 4, stream);
    k_fill_bucket<<<(NE + 255) / 256, 256, 0, stream>>>(src, dst, ea, cntN, ep);
    k_deg_dis<<<(NN * 16 + 255) / 256, 256, 0, stream>>>(cntN, ep, dis);

    // ---- layer 1 (fused through the V=30 vocab: h1 = relu(S * E1[x] + b1)) ----
    k_emb_mm<<<1, 256, 0, stream>>>(emb, Ws[0], E1);
    k_layer1<<<(NN + 3) / 4, 256, 0, stream>>>(cntN, ep, dis, x, E1, bs[0], A1);

    // ---- layer 2 ----
    k_matmul<<<(NN + 63) / 64, 256, 0, stream>>>(A1, Ws[1], B);
    k_spmm2<<<(NN + 3) / 4, 256, 0, stream>>>(cntN, ep, dis, B, bs[1], A2);

    // ---- layer 3 aggregate + pooling (fused; W3 applied after pooling) ----
    hipMemsetAsync(pool, 0, (size_t)GG * DD * 4, stream);
    hipMemsetAsync(cnt, 0, (size_t)GG * 4, stream);
    k_spmm3_pool<<<PBLK, 1024, 0, stream>>>(cntN, ep, dis, A2, batch, pool, cnt);

    // ---- mean -> W3 -> normalize ----
    k_final_mm<<<1, 1024, 0, stream>>>(pool, cnt, Ws[2], bs[2], out);
}

// Round 13
// 177.243 us; speedup vs baseline: 2.2070x; 1.0451x over previous
//
#include <hip/hip_runtime.h>
#include <hip/hip_fp16.h>

#define NN 50000     // nodes
#define NE 800000    // edges
#define DD 64        // embedding dim
#define GG 64        // graphs
#define VV 30        // node label vocab
#define CAP 48       // bucket capacity per node (in-degree ~ Poisson(16); P(>=48) ~ 1e-9)
#define PBLK 512     // blocks for fused layer3+pool
#define PCH ((NN + PBLK - 1) / PBLK)   // 98 contiguous nodes per block
#define FCH 256      // edge chunks for grouped fill

// ---- bf16 helpers (RNE) ----
__device__ inline unsigned short f2bf(float f) {
    unsigned u = __float_as_uint(f);
    return (unsigned short)((u + 0x7FFF + ((u >> 16) & 1)) >> 16);
}
__device__ inline float bf2f(unsigned short s) {
    return __uint_as_float(((unsigned)s) << 16);
}
// ---- packed edge payload: src (lo16) | fp16(ea) (hi16) ----
__device__ inline unsigned pack_edge(int s, float ea) {
    return (unsigned)s | ((unsigned)__half_as_ushort(__float2half_rn(ea)) << 16);
}
__device__ inline int unpack_src(unsigned p) { return (int)(p & 0xFFFFu); }
__device__ inline float unpack_ea(unsigned p) {
    return __half2float(__ushort_as_half((unsigned short)(p >> 16)));
}

// ------- grouped fill: group g=(dst>>4)&7 handled only by blocks with bid%8==g ----
// Round-robin dispatch places bid%8 on XCD g -> each ep/cnt line dirtied in ONE L2.
__global__ __launch_bounds__(256) void k_fill_grouped(const int* __restrict__ src,
                                                      const int* __restrict__ dst,
                                                      const float* __restrict__ ea,
                                                      int* __restrict__ cnt,
                                                      unsigned* __restrict__ ep) {
    int g = blockIdx.x & 7;
    int chunk = blockIdx.x >> 3;          // 0..FCH-1
    const int per = (NE + FCH - 1) / FCH; // 3125
    int e0 = chunk * per;
    int e1 = min(e0 + per, NE);
    for (int e = e0 + threadIdx.x; e < e1; e += 256) {
        int t = dst[e];
        if (((t >> 4) & 7) == g) {
            int p = atomicAdd(&cnt[t], 1);
            if (p < CAP) ep[(size_t)t * CAP + p] = pack_edge(src[e], ea[e]);
        }
    }
}

// ------- per-node (16 lanes): deg = 1 + sum ea; dis = deg^-1/2 --------------------
__global__ void k_deg_dis(const int* __restrict__ cnt, const unsigned* __restrict__ ep,
                          float* __restrict__ dis) {
    int tid = blockIdx.x * blockDim.x + threadIdx.x;
    int node = tid >> 4, lane = tid & 15;
    if (node >= NN) return;
    int c = min(cnt[node], CAP);
    float s = 0.f;
    for (int k = lane; k < c; k += 16) s += unpack_ea(ep[(size_t)node * CAP + k]);
    #pragma unroll
    for (int o = 8; o > 0; o >>= 1) s += __shfl_xor(s, o, 16);
    if (lane == 0) {
        s += 1.0f;                        // self loop
        dis[node] = 1.0f / sqrtf(s);
    }
}

// ------- tiny dense: E1 = emb @ W1  (30x64 @ 64x64) -------------------------------
__global__ __launch_bounds__(256) void k_emb_mm(const float* __restrict__ emb,
                                                const float* __restrict__ W,
                                                float* __restrict__ E1) {
    int t = threadIdx.x;
    int d = t & 63;
    for (int v = t >> 6; v < VV; v += 4) {
        float acc = 0.f;
        #pragma unroll
        for (int k = 0; k < 64; k++) acc = fmaf(emb[v * 64 + k], W[k * 64 + d], acc);
        E1[v * 64 + d] = acc;
    }
}

// ------- layer 1 fused: h1 = relu( sum_in w*E1[x_s] + dis^2*E1[x_i] + b1 ) --------
__global__ __launch_bounds__(256) void k_layer1(const int* __restrict__ cnt,
                                                const unsigned* __restrict__ ep,
                                                const float* __restrict__ dis,
                                                const int* __restrict__ x,
                                                const float* __restrict__ E1,
                                                const float* __restrict__ bias,
                                                unsigned short* __restrict__ A1) {
    __shared__ float El[VV * 64];
    int t = threadIdx.x;
    for (int i = t; i < VV * 64; i += 256) El[i] = E1[i];
    __syncthreads();
    int node = blockIdx.x * 4 + (t >> 6);   // 1 wave per node
    int d = t & 63;
    if (node >= NN) return;
    int c = min(cnt[node], CAP);
    const unsigned* row = ep + (size_t)node * CAP;
    unsigned pay = (d < c) ? row[d] : 0u;   // pad edges: ea=0 -> w=0
    float disn = dis[node];
    float a0 = 0.f, a1 = 0.f, a2 = 0.f, a3 = 0.f;
    int iters = (c + 7) >> 3;
    for (int it = 0; it < iters; ++it) {
        int k0 = it << 3;
        unsigned p0 = __shfl(pay, k0+0), p1 = __shfl(pay, k0+1);
        unsigned p2 = __shfl(pay, k0+2), p3 = __shfl(pay, k0+3);
        unsigned p4 = __shfl(pay, k0+4), p5 = __shfl(pay, k0+5);
        unsigned p6 = __shfl(pay, k0+6), p7 = __shfl(pay, k0+7);
        int s0 = unpack_src(p0), s1 = unpack_src(p1), s2 = unpack_src(p2), s3 = unpack_src(p3);
        int s4 = unpack_src(p4), s5 = unpack_src(p5), s6 = unpack_src(p6), s7 = unpack_src(p7);
        int x0 = x[s0], x1 = x[s1], x2 = x[s2], x3 = x[s3];
        int x4 = x[s4], x5 = x[s5], x6 = x[s6], x7 = x[s7];
        float w0 = dis[s0] * unpack_ea(p0), w1 = dis[s1] * unpack_ea(p1);
        float w2 = dis[s2] * unpack_ea(p2), w3 = dis[s3] * unpack_ea(p3);
        float w4 = dis[s4] * unpack_ea(p4), w5 = dis[s5] * unpack_ea(p5);
        float w6 = dis[s6] * unpack_ea(p6), w7 = dis[s7] * unpack_ea(p7);
        a0 = fmaf(w0, El[x0 * 64 + d], a0); a1 = fmaf(w1, El[x1 * 64 + d], a1);
        a2 = fmaf(w2, El[x2 * 64 + d], a2); a3 = fmaf(w3, El[x3 * 64 + d], a3);
        a0 = fmaf(w4, El[x4 * 64 + d], a0); a1 = fmaf(w5, El[x5 * 64 + d], a1);
        a2 = fmaf(w6, El[x6 * 64 + d], a2); a3 = fmaf(w7, El[x7 * 64 + d], a3);
    }
    float v = ((a0 + a1) + (a2 + a3)) * disn
            + El[x[node] * 64 + d] * (disn * disn) + bias[d];
    A1[(size_t)node * 64 + d] = f2bf(fmaxf(v, 0.f));
}

// -------- dense: B(bf16) = A(bf16) @ W  , W: [64,64] fp32 -------------------------
__global__ __launch_bounds__(256) void k_matmul(const unsigned short* __restrict__ A,
                                                const float* __restrict__ W,
                                                unsigned short* __restrict__ B) {
    __shared__ float Wl[64 * 64];   // [k][d]
    __shared__ float Ar[16 * 64];   // [row][k]
    int t = threadIdx.x;
    for (int i = t * 4; i < 64 * 64; i += 256 * 4)
        *(float4*)&Wl[i] = *(const float4*)&W[i];
    int q   = t & 15;       // dim quad
    int sub = t >> 4;       // row slot 0..15
    int r0 = blockIdx.x * 64;
    for (int rg = 0; rg < 64; rg += 16) {
        __syncthreads();                       // covers Wl load on first iter
        {   // stage 16 rows (1024 elems, one ushort4 per thread)
            int idx = t * 4;
            int rr = idx >> 6, kk = idx & 63;
            int r = r0 + rg + rr;
            float4 a = make_float4(0.f, 0.f, 0.f, 0.f);
            if (r < NN) {
                ushort4 u = *(const ushort4*)&A[(size_t)r * DD + kk];
                a = make_float4(bf2f(u.x), bf2f(u.y), bf2f(u.z), bf2f(u.w));
            }
            *(float4*)&Ar[idx] = a;
        }
        __syncthreads();
        int r = r0 + rg + sub;
        if (r < NN) {
            float4 acc = make_float4(0.f, 0.f, 0.f, 0.f);
            #pragma unroll
            for (int k = 0; k < 64; k++) {
                float a = Ar[sub * 64 + k];
                float4 w4 = *(float4*)&Wl[k * 64 + q * 4];
                acc.x = fmaf(a, w4.x, acc.x);
                acc.y = fmaf(a, w4.y, acc.y);
                acc.z = fmaf(a, w4.z, acc.z);
                acc.w = fmaf(a, w4.w, acc.w);
            }
            ushort4 o;
            o.x = f2bf(acc.x); o.y = f2bf(acc.y);
            o.z = f2bf(acc.z); o.w = f2bf(acc.w);
            *(ushort4*)&B[(size_t)r * DD + q * 4] = o;
        }
    }
}

// ------- SpMM gather (layer 2): A2(bf16) = relu(spmm_row + bias) ------------------
__global__ __launch_bounds__(256) void k_spmm2(const int* __restrict__ cnt,
                                               const unsigned* __restrict__ ep,
                                               const float* __restrict__ dis,
                                               const unsigned short* __restrict__ B,
                                               const float* __restrict__ bias,
                                               unsigned short* __restrict__ A2) {
    int node = blockIdx.x * 4 + (threadIdx.x >> 6);   // 1 wave per node
    int d = threadIdx.x & 63;
    if (node >= NN) return;
    int c = min(cnt[node], CAP);
    const unsigned* row = ep + (size_t)node * CAP;
    unsigned pay = (d < c) ? row[d] : 0u;
    float disn = dis[node];
    float a0 = 0.f, a1 = 0.f, a2 = 0.f, a3 = 0.f;
    int iters = (c + 7) >> 3;
    for (int it = 0; it < iters; ++it) {
        int k0 = it << 3;
        unsigned p0 = __shfl(pay, k0+0), p1 = __shfl(pay, k0+1);
        unsigned p2 = __shfl(pay, k0+2), p3 = __shfl(pay, k0+3);
        unsigned p4 = __shfl(pay, k0+4), p5 = __shfl(pay, k0+5);
        unsigned p6 = __shfl(pay, k0+6), p7 = __shfl(pay, k0+7);
        int s0 = unpack_src(p0), s1 = unpack_src(p1), s2 = unpack_src(p2), s3 = unpack_src(p3);
        int s4 = unpack_src(p4), s5 = unpack_src(p5), s6 = unpack_src(p6), s7 = unpack_src(p7);
        float g0 = bf2f(B[(size_t)s0 * 64 + d]), g1 = bf2f(B[(size_t)s1 * 64 + d]);
        float g2 = bf2f(B[(size_t)s2 * 64 + d]), g3 = bf2f(B[(size_t)s3 * 64 + d]);
        float g4 = bf2f(B[(size_t)s4 * 64 + d]), g5 = bf2f(B[(size_t)s5 * 64 + d]);
        float g6 = bf2f(B[(size_t)s6 * 64 + d]), g7 = bf2f(B[(size_t)s7 * 64 + d]);
        float w0 = dis[s0] * unpack_ea(p0), w1 = dis[s1] * unpack_ea(p1);
        float w2 = dis[s2] * unpack_ea(p2), w3 = dis[s3] * unpack_ea(p3);
        float w4 = dis[s4] * unpack_ea(p4), w5 = dis[s5] * unpack_ea(p5);
        float w6 = dis[s6] * unpack_ea(p6), w7 = dis[s7] * unpack_ea(p7);
        a0 = fmaf(w0, g0, a0); a1 = fmaf(w1, g1, a1);
        a2 = fmaf(w2, g2, a2); a3 = fmaf(w3, g3, a3);
        a0 = fmaf(w4, g4, a0); a1 = fmaf(w5, g5, a1);
        a2 = fmaf(w6, g6, a2); a3 = fmaf(w7, g7, a3);
    }
    float v = ((a0 + a1) + (a2 + a3)) * disn
            + bf2f(B[(size_t)node * 64 + d]) * (disn * disn) + bias[d];
    A2[(size_t)node * 64 + d] = f2bf(fmaxf(v, 0.f));
}

// ------- layer 3 aggregate + pool fused (NO W3 — applied after pooling) -----------
__global__ __launch_bounds__(1024) void k_spmm3_pool(const int* __restrict__ cnt,
                                                     const unsigned* __restrict__ ep,
                                                     const float* __restrict__ dis,
                                                     const unsigned short* __restrict__ A2,
                                                     const int* __restrict__ batch,
                                                     float* __restrict__ pool,
                                                     float* __restrict__ gcnt) {
    __shared__ float lpool[GG * DD];      // 16 KB
    __shared__ float lcnt[GG];
    int t = threadIdx.x;
    for (int i = t; i < GG * DD; i += 1024) lpool[i] = 0.f;
    if (t < GG) lcnt[t] = 0.f;
    __syncthreads();
    int base = blockIdx.x * PCH;
    int end = min(base + PCH, NN);
    int d = t & 63;
    for (int node = base + (t >> 6); node < end; node += 16) {   // 16 waves
        int c = min(cnt[node], CAP);
        const unsigned* row = ep + (size_t)node * CAP;
        unsigned pay = (d < c) ? row[d] : 0u;
        float disn = dis[node];
        float a0 = 0.f, a1 = 0.f, a2 = 0.f, a3 = 0.f;
        int iters = (c + 7) >> 3;
        for (int it = 0; it < iters; ++it) {
            int k0 = it << 3;
            unsigned p0 = __shfl(pay, k0+0), p1 = __shfl(pay, k0+1);
            unsigned p2 = __shfl(pay, k0+2), p3 = __shfl(pay, k0+3);
            unsigned p4 = __shfl(pay, k0+4), p5 = __shfl(pay, k0+5);
            unsigned p6 = __shfl(pay, k0+6), p7 = __shfl(pay, k0+7);
            int s0 = unpack_src(p0), s1 = unpack_src(p1), s2 = unpack_src(p2), s3 = unpack_src(p3);
            int s4 = unpack_src(p4), s5 = unpack_src(p5), s6 = unpack_src(p6), s7 = unpack_src(p7);
            float g0 = bf2f(A2[(size_t)s0 * 64 + d]), g1 = bf2f(A2[(size_t)s1 * 64 + d]);
            float g2 = bf2f(A2[(size_t)s2 * 64 + d]), g3 = bf2f(A2[(size_t)s3 * 64 + d]);
            float g4 = bf2f(A2[(size_t)s4 * 64 + d]), g5 = bf2f(A2[(size_t)s5 * 64 + d]);
            float g6 = bf2f(A2[(size_t)s6 * 64 + d]), g7 = bf2f(A2[(size_t)s7 * 64 + d]);
            float w0 = dis[s0] * unpack_ea(p0), w1 = dis[s1] * unpack_ea(p1);
            float w2 = dis[s2] * unpack_ea(p2), w3 = dis[s3] * unpack_ea(p3);
            float w4 = dis[s4] * unpack_ea(p4), w5 = dis[s5] * unpack_ea(p5);
            float w6 = dis[s6] * unpack_ea(p6), w7 = dis[s7] * unpack_ea(p7);
            a0 = fmaf(w0, g0, a0); a1 = fmaf(w1, g1, a1);
            a2 = fmaf(w2, g2, a2); a3 = fmaf(w3, g3, a3);
            a0 = fmaf(w4, g4, a0); a1 = fmaf(w5, g5, a1);
            a2 = fmaf(w6, g6, a2); a3 = fmaf(w7, g7, a3);
        }
        float v = ((a0 + a1) + (a2 + a3)) * disn
                + bf2f(A2[(size_t)node * 64 + d]) * (disn * disn);
        int g = batch[node];
        atomicAdd(&lpool[g * 64 + d], v);     // LDS atomic
        if (d == 0) atomicAdd(&lcnt[g], 1.f);
    }
    __syncthreads();
    for (int i = t; i < GG * DD; i += 1024) {
        float v = lpool[i];
        if (v != 0.f) unsafeAtomicAdd(&pool[i], v);
    }
    if (t < GG) {
        float v = lcnt[t];
        if (v != 0.f) unsafeAtomicAdd(&gcnt[t], v);
    }
}

// ------- final: mean -> @W3 + b3 -> L2 normalize  (G=64 rows, 1 block) ------------
__global__ __launch_bounds__(1024) void k_final_mm(const float* __restrict__ pool,
                                                   const float* __restrict__ gcnt,
                                                   const float* __restrict__ W3,
                                                   const float* __restrict__ b3,
                                                   float* __restrict__ out) {
    __shared__ float Wl[DD * DD];     // 16 KB [k][d]
    __shared__ float Ml[GG * DD];     // 16 KB mean rows
    int t = threadIdx.x;
    for (int i = t; i < DD * DD; i += 1024) Wl[i] = W3[i];
    for (int i = t; i < GG * DD; i += 1024) {
        int g = i >> 6;
        Ml[i] = pool[i] / fmaxf(gcnt[g], 1.0f);
    }
    __syncthreads();
    int w = t >> 6, d = t & 63;       // 16 waves, lane = output dim
    for (int g = w; g < GG; g += 16) {
        float acc = b3[d];
        #pragma unroll
        for (int k = 0; k < 64; k++) acc = fmaf(Ml[g * 64 + k], Wl[k * 64 + d], acc);
        float ss = acc * acc;
        #pragma unroll
        for (int o = 32; o > 0; o >>= 1) ss += __shfl_xor(ss, o);
        out[g * 64 + d] = acc / fmaxf(sqrtf(ss), 1e-12f);
    }
}

extern "C" void kernel_launch(void* const* d_in, const int* in_sizes, int n_in,
                              void* d_out, int out_size, void* d_ws, size_t ws_size,
                              hipStream_t stream) {
    const int*   x    = (const int*)d_in[0];
    const int*   ei   = (const int*)d_in[1];
    const int*   src  = ei;
    const int*   dst  = ei + NE;
    const float* ea   = (const float*)d_in[2];
    const int*   batch= (const int*)d_in[3];
    const float* emb  = (const float*)d_in[4];
    const float* Ws[3] = {(const float*)d_in[5], (const float*)d_in[7], (const float*)d_in[9]};
    const float* bs[3] = {(const float*)d_in[6], (const float*)d_in[8], (const float*)d_in[10]};
    float* out = (float*)d_out;

    char* ws = (char*)d_ws;
    size_t off = 0;
    auto alloc = [&](size_t nb) -> void* {
        void* p = ws + off;
        off = (off + nb + 255) & ~(size_t)255;
        return p;
    };
    float*          dis  = (float*)alloc((size_t)NN * 4);
    int*            cntN = (int*)  alloc((size_t)NN * 4);
    unsigned*       ep   = (unsigned*)alloc((size_t)NN * CAP * 4); // {src, fp16 ea}
    unsigned short* A1   = (unsigned short*)alloc((size_t)NN * DD * 2); // h1 (bf16)
    unsigned short* B    = (unsigned short*)alloc((size_t)NN * DD * 2); // h1@W2 (bf16)
    unsigned short* A2   = (unsigned short*)alloc((size_t)NN * DD * 2); // h2 (bf16)
    float*          E1   = (float*)alloc((size_t)VV * DD * 4);     // emb @ W1
    float*          pool = (float*)alloc((size_t)GG * DD * 4);
    float*          cnt  = (float*)alloc((size_t)GG * 4);

    // ---- bucketed CSR + norm preprocessing (once, reused by all 3 layers) ----
    hipMemsetAsync(cntN, 0, (size_t)NN * 4, stream);
    k_fill_grouped<<<FCH * 8, 256, 0, stream>>>(src, dst, ea, cntN, ep);
    k_deg_dis<<<(NN * 16 + 255) / 256, 256, 0, stream>>>(cntN, ep, dis);

    // ---- layer 1 (fused through the V=30 vocab: h1 = relu(S * E1[x] + b1)) ----
    k_emb_mm<<<1, 256, 0, stream>>>(emb, Ws[0], E1);
    k_layer1<<<(NN + 3) / 4, 256, 0, stream>>>(cntN, ep, dis, x, E1, bs[0], A1);

    // ---- layer 2 ----
    k_matmul<<<(NN + 63) / 64, 256, 0, stream>>>(A1, Ws[1], B);
    k_spmm2<<<(NN + 3) / 4, 256, 0, stream>>>(cntN, ep, dis, B, bs[1], A2);

    // ---- layer 3 aggregate + pooling (fused; W3 applied after pooling) ----
    hipMemsetAsync(pool, 0, (size_t)GG * DD * 4, stream);
    hipMemsetAsync(cnt, 0, (size_t)GG * 4, stream);
    k_spmm3_pool<<<PBLK, 1024, 0, stream>>>(cntN, ep, dis, A2, batch, pool, cnt);

    // ---- mean -> W3 -> normalize ----
    k_final_mm<<<1, 1024, 0, stream>>>(pool, cnt, Ws[2], bs[2], out);
}